// Round 12
// baseline (209.266 us; speedup 1.0000x reference)
//
#include <hip/hip_runtime.h>
#include <math.h>

#define N_NODES 50000
#define N_EDGES 800000
#define F_IN    128
#define HID     64
#define N_CLS   40

#define M1 (3 * HID)    // 192: [W1_0 | W1_1 | root1]
#define K2  192         // layer-2 GEMM depth: [aggw(64) | aggv(64) | h(64)]
#define C2P 64          // WT2 padded output cols (40 real + 24 zero)

#define RANGE_SZ 6250   // 50000 / 8 node ranges (one per XCD) — r0-proven permute split
#define PERM_SLICES 128
#define PERM_CHUNK (N_EDGES / PERM_SLICES)  // 6250
#define EST 64          // edata bucket stride per node (max deg ~36 at lambda=16)

#define RSPLIT 25024    // node split aligned to 64-row GEMM tiles (391*64)
#define GA_BLK (RSPLIT / 64)                       // 391 gemm_out blocks, range A
#define GB2_BLK ((N_NODES - RSPLIT + 63) / 64)     // 391 gemm_out blocks, range B
#define G2A_BLK (RSPLIT / 4)                       // 6256 gather2h blocks, range A
#define G2B_BLK ((N_NODES - RSPLIT + 3) / 4)       // 6244 gather2h blocks, range B

#define NW (M1 * F_IN + C2P * K2)   // 36864 weight elements

using sh8 = __attribute__((ext_vector_type(8))) short;
using floatx4 = __attribute__((ext_vector_type(4))) float;

__device__ inline unsigned short f2bf(float f) {
    union { float f; unsigned int u; } c{f};
    unsigned int r = (c.u + 0x7FFF + ((c.u >> 16) & 1)) >> 16;
    return (unsigned short)r;
}
__device__ inline float bf2f(unsigned int u) {
    union { unsigned int u; float f; } c;
    c.u = u << 16;
    return c.f;
}

// ---------------- weight concat (both layers) + cnt zeroing, one launch ----------
// WT1: [192 cols][128 k], k contiguous.
// WT2: [64 cols][192 k], k contiguous; cols 40..63 zero (guard-free MFMA B loads).
__global__ void concat_w(const float* __restrict__ W1, const float* __restrict__ root1,
                         const float* __restrict__ W2, const float* __restrict__ root2,
                         unsigned short* __restrict__ WT1, unsigned short* __restrict__ WT2,
                         int* __restrict__ cnt) {
    int i = blockIdx.x * blockDim.x + threadIdx.x;
    if (i < M1 * F_IN) {
        int c = i / F_IN, k = i % F_IN;
        float val;
        if (c < HID)            val = W1[k * HID + c];
        else if (c < 2 * HID)   val = W1[F_IN * HID + k * HID + (c - HID)];
        else                    val = root1[k * HID + (c - 2 * HID)];
        WT1[i] = f2bf(val);
    } else if (i < NW) {
        int ii = i - M1 * F_IN;          // ii = c*192 + k
        int c = ii / K2, k = ii % K2;
        float val = 0.0f;
        if (c < N_CLS) {
            if (k < HID)             val = W2[k * N_CLS + c];
            else if (k < 2 * HID)    val = W2[HID * N_CLS + (k - HID) * N_CLS + c];
            else                     val = root2[(k - 2 * HID) * N_CLS + c];
        }
        WT2[ii] = f2bf(val);
    } else {
        int ii = i - NW;
        if (ii < N_NODES) cnt[ii] = 0;
    }
}

// ---------------- layer-1 gemm body (r0/r8-proven): 64-row tile, 3 column tiles ----------
template <int KD, bool AF32, int SPLIT, int PW, int ROOTW, int MT>
__device__ __forceinline__ void gemm_body(int bid, const void* __restrict__ Aptr,
                                          const unsigned short* __restrict__ Bt,
                                          unsigned short* __restrict__ Csp,
                                          float* __restrict__ Croot, int Crows) {
    constexpr int KP = KD + 8;
    __shared__ unsigned short As[64 * KP];
    __shared__ unsigned short Bs[64 * KP];

    int tid = threadIdx.x;
    int row0 = bid * 64;

    if (AF32) {
        const float* A = (const float*)Aptr;
        for (int c = tid; c < 64 * (KD / 4); c += 256) {
            int r = c / (KD / 4), q = c % (KD / 4);
            int gr = row0 + r;
            float4 v = make_float4(0.f, 0.f, 0.f, 0.f);
            if (gr < Crows) v = *(const float4*)(A + (size_t)gr * KD + q * 4);
            union { unsigned short s[4]; uint2 u; } pk;
            pk.s[0] = f2bf(v.x); pk.s[1] = f2bf(v.y);
            pk.s[2] = f2bf(v.z); pk.s[3] = f2bf(v.w);
            *(uint2*)&As[r * KP + q * 4] = pk.u;
        }
    } else {
        const unsigned short* A = (const unsigned short*)Aptr;
        for (int c = tid; c < 64 * (KD / 8); c += 256) {
            int r = c / (KD / 8), q = c % (KD / 8);
            int gr = row0 + r;
            sh8 v = {};
            if (gr < Crows) v = *(const sh8*)(A + (size_t)gr * KD + q * 8);
            *(sh8*)&As[r * KP + q * 8] = v;
        }
    }

    int wv = tid >> 6, lane = tid & 63;
    int lrow = lane & 15, lq = lane >> 4;

    for (int mt = 0; mt < MT; ++mt) {
        int c0 = mt * 64;
        __syncthreads();
        for (int c = tid; c < 64 * (KD / 8); c += 256) {
            int r = c / (KD / 8), q = c % (KD / 8);
            *(sh8*)&Bs[r * KP + q * 8] = *(const sh8*)(Bt + (size_t)(c0 + r) * KD + q * 8);
        }
        __syncthreads();

        floatx4 acc[4] = {{0.f,0.f,0.f,0.f},{0.f,0.f,0.f,0.f},{0.f,0.f,0.f,0.f},{0.f,0.f,0.f,0.f}};
#pragma unroll
        for (int kt = 0; kt < KD / 32; ++kt) {
            int kb = kt * 32 + lq * 8;
            sh8 a0 = *(const sh8*)&As[(wv * 16 + lrow) * KP + kb];
#pragma unroll
            for (int cf = 0; cf < 4; ++cf) {
                sh8 b = *(const sh8*)&Bs[(cf * 16 + lrow) * KP + kb];
                acc[cf] = __builtin_amdgcn_mfma_f32_16x16x32_bf16(a0, b, acc[cf], 0, 0, 0);
            }
        }

#pragma unroll
        for (int r = 0; r < 4; ++r) {
            int gr = row0 + wv * 16 + lq * 4 + r;
            if (gr >= Crows) continue;
#pragma unroll
            for (int cf = 0; cf < 4; ++cf) {
                int gc = c0 + cf * 16 + lrow;
                float val = acc[cf][r];
                if (gc < SPLIT) {
                    int pi = (gc < PW) ? gc * 2 : (gc - PW) * 2 + 1;
                    Csp[(size_t)gr * SPLIT + pi] = f2bf(val);
                } else if (gc < SPLIT + ROOTW) {
                    Croot[(size_t)gr * ROOTW + (gc - SPLIT)] = val;
                }
            }
        }
    }
}

// XCD-range-partitioned bucketed permute (r0-proven): cnt is histogram and cursor.
__device__ __forceinline__ void permute_body(int b, const int* __restrict__ src,
                                             const int* __restrict__ dst,
                                             const float* __restrict__ attr,
                                             int* __restrict__ cnt,
                                             unsigned int* __restrict__ edata) {
    int range = b & 7;
    int slice = b >> 3;
    int lo = range * RANGE_SZ;
    int e0 = slice * PERM_CHUNK;
    int e1 = e0 + PERM_CHUNK;
    for (int e = e0 + (int)threadIdx.x; e < e1; e += 256) {
        int d = dst[e];
        if ((unsigned)(d - lo) < (unsigned)RANGE_SZ) {
            int pos = atomicAdd(&cnt[d], 1);
            if (pos < EST) {
                unsigned int q = (unsigned int)(attr[e] * 65535.0f + 0.5f);
                edata[d * EST + pos] = (unsigned int)src[e] | (q << 16);
            }
        }
    }
}

// ---------------- fused layer-1 GEMM + full permute (r8-proven: 67 us) ----------
__global__ __launch_bounds__(256) void gemm1_permute(const float* __restrict__ x,
                                                     const unsigned short* __restrict__ WT1,
                                                     unsigned short* __restrict__ Ysp,
                                                     float* __restrict__ Yroot,
                                                     const int* __restrict__ src,
                                                     const int* __restrict__ dst,
                                                     const float* __restrict__ attr,
                                                     int* __restrict__ cnt,
                                                     unsigned int* __restrict__ edata,
                                                     int gemmBlocks) {
    if ((int)blockIdx.x < gemmBlocks) {
        gemm_body<128, true, 128, 64, 64, 3>(blockIdx.x, (const void*)x, WT1, Ysp, Yroot, N_NODES);
    } else {
        permute_body(blockIdx.x - gemmBlocks, src, dst, attr, cnt, edata);
    }
}

// ---------------- gather layer 1 (r7/r11-proven): half-wave edge pairing, hb only ----------
__global__ __launch_bounds__(256) void gather1(const unsigned short* __restrict__ Ysp,
                                               const float* __restrict__ Yroot,
                                               const int* __restrict__ cnt,
                                               const unsigned int* __restrict__ edata,
                                               const float* __restrict__ bias1,
                                               unsigned short* __restrict__ h) {
    int wave = (blockIdx.x * blockDim.x + threadIdx.x) >> 6;
    int lane = threadIdx.x & 63;
    if (wave >= N_NODES) return;
    int hf = lane >> 5;       // edge stream (0: even edges, 1: odd edges)
    int c  = lane & 31;       // feature pair -> features 2c, 2c+1
    int deg = cnt[wave];
    deg = deg > EST ? EST : deg;
    const unsigned int* eb = edata + (size_t)wave * EST;
    const float qs = 1.0f / 65535.0f;
    float a0 = 0.0f, a1 = 0.0f;
    if (deg <= 16) {
        unsigned int e[8]; uint2 p[8];
#pragma unroll
        for (int t = 0; t < 8; ++t) e[t] = eb[2 * t + hf];
#pragma unroll
        for (int t = 0; t < 8; ++t) {
            int idx = (2 * t + hf < deg) ? (int)(e[t] & 0xffffu) : 0;
            p[t] = *(const uint2*)(Ysp + (size_t)idx * 128 + c * 4);
        }
#pragma unroll
        for (int t = 0; t < 8; ++t) {
            float m = (2 * t + hf < deg) ? 1.0f : 0.0f;
            float v = (float)(e[t] >> 16) * qs;
            float w = 1.0f - v;
            a0 += m * (w * bf2f(p[t].x & 0xffffu) + v * bf2f(p[t].x >> 16));
            a1 += m * (w * bf2f(p[t].y & 0xffffu) + v * bf2f(p[t].y >> 16));
        }
    } else {
        unsigned int e[16]; uint2 p[16];
#pragma unroll
        for (int t = 0; t < 16; ++t) e[t] = eb[2 * t + hf];
#pragma unroll
        for (int t = 0; t < 16; ++t) {
            int idx = (2 * t + hf < deg) ? (int)(e[t] & 0xffffu) : 0;
            p[t] = *(const uint2*)(Ysp + (size_t)idx * 128 + c * 4);
        }
#pragma unroll
        for (int t = 0; t < 16; ++t) {
            float m = (2 * t + hf < deg) ? 1.0f : 0.0f;
            float v = (float)(e[t] >> 16) * qs;
            float w = 1.0f - v;
            a0 += m * (w * bf2f(p[t].x & 0xffffu) + v * bf2f(p[t].x >> 16));
            a1 += m * (w * bf2f(p[t].y & 0xffffu) + v * bf2f(p[t].y >> 16));
        }
        if (deg > 32) {  // rare (P ~ 1e-4 per node)
            for (int j = 32 + hf; j < deg; j += 2) {
                unsigned int ee = eb[j];
                int idx = (int)(ee & 0xffffu);
                uint2 pp = *(const uint2*)(Ysp + (size_t)idx * 128 + c * 4);
                float v = (float)(ee >> 16) * qs;
                float w = 1.0f - v;
                a0 += w * bf2f(pp.x & 0xffffu) + v * bf2f(pp.x >> 16);
                a1 += w * bf2f(pp.y & 0xffffu) + v * bf2f(pp.y >> 16);
            }
        }
    }
    a0 += __shfl_xor(a0, 32);
    a1 += __shfl_xor(a1, 32);
    float dg = (float)deg;
    dg = dg > 1.0f ? dg : 1.0f;
    float2 yr = *(const float2*)(Yroot + (size_t)wave * HID + c * 2);
    float2 bi = *(const float2*)(bias1 + c * 2);
    float m0 = a0 / dg + yr.x + bi.x;
    float m1 = a1 / dg + yr.y + bi.y;
    m0 = m0 > 0.0f ? m0 : expm1f(m0);  // ELU
    m1 = m1 > 0.0f ? m1 : expm1f(m1);
    if (hf == 0) {
        unsigned int u = (unsigned int)f2bf(m0) | ((unsigned int)f2bf(m1) << 16);
        *(unsigned int*)(h + (size_t)wave * HID + c * 2) = u;
    }
}

// ---------------- layer-2 gather body (r8/r11-proven), node-range form ----------
__device__ __forceinline__ void gather2h_body(int local_bid, int n0, int ncount,
                                              const unsigned short* __restrict__ hb,
                                              const int* __restrict__ cnt,
                                              const unsigned int* __restrict__ edata,
                                              unsigned short* __restrict__ A128) {
    int wl = local_bid * 4 + ((int)threadIdx.x >> 6);
    int lane = threadIdx.x & 63;
    if (wl >= ncount) return;
    int node = n0 + wl;
    int hf = lane >> 5;       // edge stream
    int c  = lane & 31;       // feature pair -> features 2c, 2c+1
    int deg = cnt[node];
    deg = deg > EST ? EST : deg;
    const unsigned int* eb = edata + (size_t)node * EST;
    const float qs = 1.0f / 65535.0f;
    float a00 = 0.0f, a01 = 0.0f, a10 = 0.0f, a11 = 0.0f;
    if (deg <= 16) {
        unsigned int e[8], p[8];
#pragma unroll
        for (int t = 0; t < 8; ++t) e[t] = eb[2 * t + hf];
#pragma unroll
        for (int t = 0; t < 8; ++t) {
            int idx = (2 * t + hf < deg) ? (int)(e[t] & 0xffffu) : 0;
            p[t] = *(const unsigned int*)(hb + (size_t)idx * HID + c * 2);
        }
#pragma unroll
        for (int t = 0; t < 8; ++t) {
            float m = (2 * t + hf < deg) ? 1.0f : 0.0f;
            float v = (float)(e[t] >> 16) * qs;
            float wm = m * (1.0f - v), vm = m * v;
            float h0 = bf2f(p[t] & 0xffffu), h1 = bf2f(p[t] >> 16);
            a00 += wm * h0; a01 += wm * h1;
            a10 += vm * h0; a11 += vm * h1;
        }
    } else {
        unsigned int e[16], p[16];
#pragma unroll
        for (int t = 0; t < 16; ++t) e[t] = eb[2 * t + hf];
#pragma unroll
        for (int t = 0; t < 16; ++t) {
            int idx = (2 * t + hf < deg) ? (int)(e[t] & 0xffffu) : 0;
            p[t] = *(const unsigned int*)(hb + (size_t)idx * HID + c * 2);
        }
#pragma unroll
        for (int t = 0; t < 16; ++t) {
            float m = (2 * t + hf < deg) ? 1.0f : 0.0f;
            float v = (float)(e[t] >> 16) * qs;
            float wm = m * (1.0f - v), vm = m * v;
            float h0 = bf2f(p[t] & 0xffffu), h1 = bf2f(p[t] >> 16);
            a00 += wm * h0; a01 += wm * h1;
            a10 += vm * h0; a11 += vm * h1;
        }
        if (deg > 32) {
            for (int j = 32 + hf; j < deg; j += 2) {
                unsigned int ee = eb[j];
                int idx = (int)(ee & 0xffffu);
                unsigned int pp = *(const unsigned int*)(hb + (size_t)idx * HID + c * 2);
                float v = (float)(ee >> 16) * qs;
                float w = 1.0f - v;
                float h0 = bf2f(pp & 0xffffu), h1 = bf2f(pp >> 16);
                a00 += w * h0; a01 += w * h1;
                a10 += v * h0; a11 += v * h1;
            }
        }
    }
    a00 += __shfl_xor(a00, 32);
    a01 += __shfl_xor(a01, 32);
    a10 += __shfl_xor(a10, 32);
    a11 += __shfl_xor(a11, 32);
    if (hf == 0) {
        float dg = (float)deg;
        dg = dg > 1.0f ? dg : 1.0f;
        float inv = 1.0f / dg;
        unsigned int u0 = (unsigned int)f2bf(a00 * inv) | ((unsigned int)f2bf(a01 * inv) << 16);
        unsigned int u1 = (unsigned int)f2bf(a10 * inv) | ((unsigned int)f2bf(a11 * inv) << 16);
        *(unsigned int*)(A128 + (size_t)node * 128 + c * 2) = u0;
        *(unsigned int*)(A128 + (size_t)node * 128 + 64 + c * 2) = u1;
    }
}

// ---------------- layer-2 output GEMM body (r10/r11-proven), row-base form ----------
__device__ __forceinline__ void gemm_out_body(int bid, int rowbase,
                                              const unsigned short* __restrict__ A128,
                                              const unsigned short* __restrict__ hb,
                                              const unsigned short* __restrict__ WT2,
                                              const float* __restrict__ bias2,
                                              float* __restrict__ out) {
    constexpr int KD = K2, KP = KD + 8;      // 200
    __shared__ unsigned short As[64 * KP];   // 25.6 KB
    int tid = threadIdx.x;
    int row0 = rowbase + bid * 64;

    for (int cidx = tid; cidx < 64 * (KD / 8); cidx += 256) {  // 1536 sh8 chunks
        int r = cidx / (KD / 8), q = cidx % (KD / 8);
        int gr = row0 + r;
        sh8 v = {};
        if (gr < N_NODES) {
            if (q < 16) v = *(const sh8*)(A128 + (size_t)gr * 128 + q * 8);
            else        v = *(const sh8*)(hb + (size_t)gr * 64 + (q - 16) * 8);
        }
        *(sh8*)&As[r * KP + q * 8] = v;
    }
    __syncthreads();

    int wv = tid >> 6, lane = tid & 63;
    int lrow = lane & 15, lq = lane >> 4;
    floatx4 acc[4] = {{0.f,0.f,0.f,0.f},{0.f,0.f,0.f,0.f},{0.f,0.f,0.f,0.f},{0.f,0.f,0.f,0.f}};
#pragma unroll
    for (int kt = 0; kt < KD / 32; ++kt) {   // 6
        int kb = kt * 32 + lq * 8;
        sh8 a0 = *(const sh8*)&As[(wv * 16 + lrow) * KP + kb];
#pragma unroll
        for (int cf = 0; cf < 4; ++cf) {
            sh8 b = *(const sh8*)(WT2 + (size_t)(cf * 16 + lrow) * KD + kb);
            acc[cf] = __builtin_amdgcn_mfma_f32_16x16x32_bf16(a0, b, acc[cf], 0, 0, 0);
        }
    }
#pragma unroll
    for (int r = 0; r < 4; ++r) {
        int gr = row0 + wv * 16 + lq * 4 + r;
        if (gr >= N_NODES) continue;
#pragma unroll
        for (int cf = 0; cf < 4; ++cf) {
            int gc = cf * 16 + lrow;
            if (gc < N_CLS) {
                out[(size_t)gr * N_CLS + gc] = acc[cf][r] + bias2[gc];
            }
        }
    }
}

// ---------------- stage 4: gather2h range A ----------
__global__ __launch_bounds__(256) void g2hA(const unsigned short* __restrict__ hb,
                                            const int* __restrict__ cnt,
                                            const unsigned int* __restrict__ edata,
                                            unsigned short* __restrict__ A128) {
    gather2h_body(blockIdx.x, 0, RSPLIT, hb, cnt, edata, A128);
}

// ---------------- stage 5: gather2h range B ∥ gemm_out range A ----------
// Legal: gemm_out rows < RSPLIT read A128/hb rows < RSPLIT (complete after stage 4);
// g2hB writes A128 rows >= RSPLIT only. gemm_out is MFMA-dense -> real overlap.
__global__ __launch_bounds__(256) void g2hB_outA(const unsigned short* __restrict__ hb,
                                                 const int* __restrict__ cnt,
                                                 const unsigned int* __restrict__ edata,
                                                 unsigned short* __restrict__ A128,
                                                 const unsigned short* __restrict__ WT2,
                                                 const float* __restrict__ bias2,
                                                 float* __restrict__ out) {
    if ((int)blockIdx.x < G2B_BLK) {
        gather2h_body(blockIdx.x, RSPLIT, N_NODES - RSPLIT, hb, cnt, edata, A128);
    } else {
        gemm_out_body(blockIdx.x - G2B_BLK, 0, A128, hb, WT2, bias2, out);
    }
}

// ---------------- stage 6: gemm_out range B ----------
__global__ __launch_bounds__(256) void outB(const unsigned short* __restrict__ A128,
                                            const unsigned short* __restrict__ hb,
                                            const unsigned short* __restrict__ WT2,
                                            const float* __restrict__ bias2,
                                            float* __restrict__ out) {
    gemm_out_body(blockIdx.x, RSPLIT, A128, hb, WT2, bias2, out);
}

extern "C" void kernel_launch(void* const* d_in, const int* in_sizes, int n_in,
                              void* d_out, int out_size, void* d_ws, size_t ws_size,
                              hipStream_t stream) {
    const float* x     = (const float*)d_in[0];
    const int*   eidx  = (const int*)d_in[1];
    const float* eattr = (const float*)d_in[2];
    const float* W1    = (const float*)d_in[3];
    const float* root1 = (const float*)d_in[4];
    const float* bias1 = (const float*)d_in[5];
    const float* W2    = (const float*)d_in[6];
    const float* root2 = (const float*)d_in[7];
    const float* bias2 = (const float*)d_in[8];
    float* out = (float*)d_out;

    const int* src = eidx;
    const int* dst = eidx + N_EDGES;

    // workspace layout (bytes)
    char* base = (char*)d_ws;
    unsigned short* Ysp   = (unsigned short*)base;               // 50000*128*2 = 12,800,000
    float*          Yroot = (float*)(base + 12800000);           // 50000*64*4 = 12,800,000
    unsigned short* hb    = (unsigned short*)(base + 25600000);  // 50000*64*2 = 6,400,000
    unsigned short* WT1   = (unsigned short*)(base + 32000000);  // 192*128*2 = 49,152
    unsigned short* WT2   = (unsigned short*)(base + 32049152);  // 64*192*2 = 24,576
    unsigned int*   edata = (unsigned int*)(base + 32073728);    // 50000*64*4 = 12,800,000
    int*            cnt   = (int*)(base + 44873728);             // 50,000*4 = 200,000
    unsigned short* A128  = (unsigned short*)(base + 45073728);  // 50000*128*2 = 12,800,000

    const int GB = (N_NODES + 63) / 64;  // 782 gemm blocks

    // ---- stage 1: weights + cnt zeroing ----
    hipLaunchKernelGGL(concat_w, dim3((NW + N_NODES + 255) / 256), dim3(256), 0, stream,
                       W1, root1, W2, root2, WT1, WT2, cnt);

    // ---- stage 2: layer-1 GEMM fused with full bucketed permute (r8-proven) ----
    hipLaunchKernelGGL(gemm1_permute, dim3(GB + 8 * PERM_SLICES), dim3(256), 0, stream,
                       x, WT1, Ysp, Yroot, src, dst, eattr, cnt, edata, GB);

    // ---- stage 3: layer-1 gather ----
    hipLaunchKernelGGL(gather1, dim3((N_NODES * 64 + 255) / 256), dim3(256), 0, stream,
                       Ysp, Yroot, cnt, edata, bias1, hb);

    // ---- stage 4: layer-2 gather, range A ----
    hipLaunchKernelGGL(g2hA, dim3(G2A_BLK), dim3(256), 0, stream,
                       hb, cnt, edata, A128);

    // ---- stage 5: layer-2 gather range B ∥ output GEMM range A ----
    hipLaunchKernelGGL(g2hB_outA, dim3(G2B_BLK + GA_BLK), dim3(256), 0, stream,
                       hb, cnt, edata, A128, WT2, bias2, out);

    // ---- stage 6: output GEMM range B ----
    hipLaunchKernelGGL(outB, dim3(GB2_BLK), dim3(256), 0, stream,
                       A128, hb, WT2, bias2, out);
}

// Round 13
// 198.324 us; speedup vs baseline: 1.0552x; 1.0552x over previous
//
#include <hip/hip_runtime.h>
#include <math.h>

#define N_NODES 50000
#define N_EDGES 800000
#define F_IN    128
#define HID     64
#define N_CLS   40

#define M1 (3 * HID)    // 192: [W1_0 | W1_1 | root1]
#define K2  192         // layer-2 GEMM depth: [aggw(64) | aggv(64) | h(64)]
#define C2P 64          // WT2 padded output cols (40 real + 24 zero)

#define RANGE_SZ 6250   // 50000 / 8 node ranges (one per XCD) — r0-proven permute split
#define PERM_SLICES 128
#define PERM_CHUNK (N_EDGES / PERM_SLICES)  // 6250
#define EST 64          // edata bucket stride per node (max deg ~36 at lambda=16)

#define NW (M1 * F_IN + C2P * K2)   // 36864 weight elements

using sh8 = __attribute__((ext_vector_type(8))) short;
using floatx4 = __attribute__((ext_vector_type(4))) float;

__device__ inline unsigned short f2bf(float f) {
    union { float f; unsigned int u; } c{f};
    unsigned int r = (c.u + 0x7FFF + ((c.u >> 16) & 1)) >> 16;
    return (unsigned short)r;
}
__device__ inline float bf2f(unsigned int u) {
    union { unsigned int u; float f; } c;
    c.u = u << 16;
    return c.f;
}

// ---------------- weight concat (both layers) + cnt zeroing, one launch ----------
// WT1: [192 cols][128 k], k contiguous.
// WT2: [64 cols][192 k], k contiguous; cols 40..63 zero (guard-free MFMA B loads).
__global__ void concat_w(const float* __restrict__ W1, const float* __restrict__ root1,
                         const float* __restrict__ W2, const float* __restrict__ root2,
                         unsigned short* __restrict__ WT1, unsigned short* __restrict__ WT2,
                         int* __restrict__ cnt) {
    int i = blockIdx.x * blockDim.x + threadIdx.x;
    if (i < M1 * F_IN) {
        int c = i / F_IN, k = i % F_IN;
        float val;
        if (c < HID)            val = W1[k * HID + c];
        else if (c < 2 * HID)   val = W1[F_IN * HID + k * HID + (c - HID)];
        else                    val = root1[k * HID + (c - 2 * HID)];
        WT1[i] = f2bf(val);
    } else if (i < NW) {
        int ii = i - M1 * F_IN;          // ii = c*192 + k
        int c = ii / K2, k = ii % K2;
        float val = 0.0f;
        if (c < N_CLS) {
            if (k < HID)             val = W2[k * N_CLS + c];
            else if (k < 2 * HID)    val = W2[HID * N_CLS + (k - HID) * N_CLS + c];
            else                     val = root2[(k - 2 * HID) * N_CLS + c];
        }
        WT2[ii] = f2bf(val);
    } else {
        int ii = i - NW;
        if (ii < N_NODES) cnt[ii] = 0;
    }
}

// ---------------- layer-1 gemm body (r0/r8-proven): 64-row tile, 3 column tiles ----------
template <int KD, bool AF32, int SPLIT, int PW, int ROOTW, int MT>
__device__ __forceinline__ void gemm_body(int bid, const void* __restrict__ Aptr,
                                          const unsigned short* __restrict__ Bt,
                                          unsigned short* __restrict__ Csp,
                                          float* __restrict__ Croot, int Crows) {
    constexpr int KP = KD + 8;
    __shared__ unsigned short As[64 * KP];
    __shared__ unsigned short Bs[64 * KP];

    int tid = threadIdx.x;
    int row0 = bid * 64;

    if (AF32) {
        const float* A = (const float*)Aptr;
        for (int c = tid; c < 64 * (KD / 4); c += 256) {
            int r = c / (KD / 4), q = c % (KD / 4);
            int gr = row0 + r;
            float4 v = make_float4(0.f, 0.f, 0.f, 0.f);
            if (gr < Crows) v = *(const float4*)(A + (size_t)gr * KD + q * 4);
            union { unsigned short s[4]; uint2 u; } pk;
            pk.s[0] = f2bf(v.x); pk.s[1] = f2bf(v.y);
            pk.s[2] = f2bf(v.z); pk.s[3] = f2bf(v.w);
            *(uint2*)&As[r * KP + q * 4] = pk.u;
        }
    } else {
        const unsigned short* A = (const unsigned short*)Aptr;
        for (int c = tid; c < 64 * (KD / 8); c += 256) {
            int r = c / (KD / 8), q = c % (KD / 8);
            int gr = row0 + r;
            sh8 v = {};
            if (gr < Crows) v = *(const sh8*)(A + (size_t)gr * KD + q * 8);
            *(sh8*)&As[r * KP + q * 8] = v;
        }
    }

    int wv = tid >> 6, lane = tid & 63;
    int lrow = lane & 15, lq = lane >> 4;

    for (int mt = 0; mt < MT; ++mt) {
        int c0 = mt * 64;
        __syncthreads();
        for (int c = tid; c < 64 * (KD / 8); c += 256) {
            int r = c / (KD / 8), q = c % (KD / 8);
            *(sh8*)&Bs[r * KP + q * 8] = *(const sh8*)(Bt + (size_t)(c0 + r) * KD + q * 8);
        }
        __syncthreads();

        floatx4 acc[4] = {{0.f,0.f,0.f,0.f},{0.f,0.f,0.f,0.f},{0.f,0.f,0.f,0.f},{0.f,0.f,0.f,0.f}};
#pragma unroll
        for (int kt = 0; kt < KD / 32; ++kt) {
            int kb = kt * 32 + lq * 8;
            sh8 a0 = *(const sh8*)&As[(wv * 16 + lrow) * KP + kb];
#pragma unroll
            for (int cf = 0; cf < 4; ++cf) {
                sh8 b = *(const sh8*)&Bs[(cf * 16 + lrow) * KP + kb];
                acc[cf] = __builtin_amdgcn_mfma_f32_16x16x32_bf16(a0, b, acc[cf], 0, 0, 0);
            }
        }

#pragma unroll
        for (int r = 0; r < 4; ++r) {
            int gr = row0 + wv * 16 + lq * 4 + r;
            if (gr >= Crows) continue;
#pragma unroll
            for (int cf = 0; cf < 4; ++cf) {
                int gc = c0 + cf * 16 + lrow;
                float val = acc[cf][r];
                if (gc < SPLIT) {
                    int pi = (gc < PW) ? gc * 2 : (gc - PW) * 2 + 1;
                    Csp[(size_t)gr * SPLIT + pi] = f2bf(val);
                } else if (gc < SPLIT + ROOTW) {
                    Croot[(size_t)gr * ROOTW + (gc - SPLIT)] = val;
                }
            }
        }
    }
}

// XCD-range-partitioned bucketed permute (r0-proven): cnt is histogram and cursor.
__device__ __forceinline__ void permute_body(int b, const int* __restrict__ src,
                                             const int* __restrict__ dst,
                                             const float* __restrict__ attr,
                                             int* __restrict__ cnt,
                                             unsigned int* __restrict__ edata) {
    int range = b & 7;
    int slice = b >> 3;
    int lo = range * RANGE_SZ;
    int e0 = slice * PERM_CHUNK;
    int e1 = e0 + PERM_CHUNK;
    for (int e = e0 + (int)threadIdx.x; e < e1; e += 256) {
        int d = dst[e];
        if ((unsigned)(d - lo) < (unsigned)RANGE_SZ) {
            int pos = atomicAdd(&cnt[d], 1);
            if (pos < EST) {
                unsigned int q = (unsigned int)(attr[e] * 65535.0f + 0.5f);
                edata[d * EST + pos] = (unsigned int)src[e] | (q << 16);
            }
        }
    }
}

// ---------------- fused layer-1 GEMM + full permute (r8-proven: 67 us) ----------
__global__ __launch_bounds__(256) void gemm1_permute(const float* __restrict__ x,
                                                     const unsigned short* __restrict__ WT1,
                                                     unsigned short* __restrict__ Ysp,
                                                     float* __restrict__ Yroot,
                                                     const int* __restrict__ src,
                                                     const int* __restrict__ dst,
                                                     const float* __restrict__ attr,
                                                     int* __restrict__ cnt,
                                                     unsigned int* __restrict__ edata,
                                                     int gemmBlocks) {
    if ((int)blockIdx.x < gemmBlocks) {
        gemm_body<128, true, 128, 64, 64, 3>(blockIdx.x, (const void*)x, WT1, Ysp, Yroot, N_NODES);
    } else {
        permute_body(blockIdx.x - gemmBlocks, src, dst, attr, cnt, edata);
    }
}

// ---------------- gather layer 1 (r7/r11-proven): half-wave edge pairing, hb only ----------
__global__ __launch_bounds__(256) void gather1(const unsigned short* __restrict__ Ysp,
                                               const float* __restrict__ Yroot,
                                               const int* __restrict__ cnt,
                                               const unsigned int* __restrict__ edata,
                                               const float* __restrict__ bias1,
                                               unsigned short* __restrict__ h) {
    int wave = (blockIdx.x * blockDim.x + threadIdx.x) >> 6;
    int lane = threadIdx.x & 63;
    if (wave >= N_NODES) return;
    int hf = lane >> 5;       // edge stream (0: even edges, 1: odd edges)
    int c  = lane & 31;       // feature pair -> features 2c, 2c+1
    int deg = cnt[wave];
    deg = deg > EST ? EST : deg;
    const unsigned int* eb = edata + (size_t)wave * EST;
    const float qs = 1.0f / 65535.0f;
    float a0 = 0.0f, a1 = 0.0f;
    if (deg <= 16) {
        unsigned int e[8]; uint2 p[8];
#pragma unroll
        for (int t = 0; t < 8; ++t) e[t] = eb[2 * t + hf];
#pragma unroll
        for (int t = 0; t < 8; ++t) {
            int idx = (2 * t + hf < deg) ? (int)(e[t] & 0xffffu) : 0;
            p[t] = *(const uint2*)(Ysp + (size_t)idx * 128 + c * 4);
        }
#pragma unroll
        for (int t = 0; t < 8; ++t) {
            float m = (2 * t + hf < deg) ? 1.0f : 0.0f;
            float v = (float)(e[t] >> 16) * qs;
            float w = 1.0f - v;
            a0 += m * (w * bf2f(p[t].x & 0xffffu) + v * bf2f(p[t].x >> 16));
            a1 += m * (w * bf2f(p[t].y & 0xffffu) + v * bf2f(p[t].y >> 16));
        }
    } else {
        unsigned int e[16]; uint2 p[16];
#pragma unroll
        for (int t = 0; t < 16; ++t) e[t] = eb[2 * t + hf];
#pragma unroll
        for (int t = 0; t < 16; ++t) {
            int idx = (2 * t + hf < deg) ? (int)(e[t] & 0xffffu) : 0;
            p[t] = *(const uint2*)(Ysp + (size_t)idx * 128 + c * 4);
        }
#pragma unroll
        for (int t = 0; t < 16; ++t) {
            float m = (2 * t + hf < deg) ? 1.0f : 0.0f;
            float v = (float)(e[t] >> 16) * qs;
            float w = 1.0f - v;
            a0 += m * (w * bf2f(p[t].x & 0xffffu) + v * bf2f(p[t].x >> 16));
            a1 += m * (w * bf2f(p[t].y & 0xffffu) + v * bf2f(p[t].y >> 16));
        }
        if (deg > 32) {  // rare (P ~ 1e-4 per node)
            for (int j = 32 + hf; j < deg; j += 2) {
                unsigned int ee = eb[j];
                int idx = (int)(ee & 0xffffu);
                uint2 pp = *(const uint2*)(Ysp + (size_t)idx * 128 + c * 4);
                float v = (float)(ee >> 16) * qs;
                float w = 1.0f - v;
                a0 += w * bf2f(pp.x & 0xffffu) + v * bf2f(pp.x >> 16);
                a1 += w * bf2f(pp.y & 0xffffu) + v * bf2f(pp.y >> 16);
            }
        }
    }
    a0 += __shfl_xor(a0, 32);
    a1 += __shfl_xor(a1, 32);
    float dg = (float)deg;
    dg = dg > 1.0f ? dg : 1.0f;
    float2 yr = *(const float2*)(Yroot + (size_t)wave * HID + c * 2);
    float2 bi = *(const float2*)(bias1 + c * 2);
    float m0 = a0 / dg + yr.x + bi.x;
    float m1 = a1 / dg + yr.y + bi.y;
    m0 = m0 > 0.0f ? m0 : expm1f(m0);  // ELU
    m1 = m1 > 0.0f ? m1 : expm1f(m1);
    if (hf == 0) {
        unsigned int u = (unsigned int)f2bf(m0) | ((unsigned int)f2bf(m1) << 16);
        *(unsigned int*)(h + (size_t)wave * HID + c * 2) = u;
    }
}

// ---------------- layer-2 gather in h-space (r8/r10-proven) -> A128, full range ----------
__global__ __launch_bounds__(256) void gather2h(const unsigned short* __restrict__ hb,
                                                const int* __restrict__ cnt,
                                                const unsigned int* __restrict__ edata,
                                                unsigned short* __restrict__ A128) {
    int wave = (blockIdx.x * blockDim.x + threadIdx.x) >> 6;
    int lane = threadIdx.x & 63;
    if (wave >= N_NODES) return;
    int hf = lane >> 5;       // edge stream
    int c  = lane & 31;       // feature pair -> features 2c, 2c+1
    int deg = cnt[wave];
    deg = deg > EST ? EST : deg;
    const unsigned int* eb = edata + (size_t)wave * EST;
    const float qs = 1.0f / 65535.0f;
    float a00 = 0.0f, a01 = 0.0f, a10 = 0.0f, a11 = 0.0f;
    if (deg <= 16) {
        unsigned int e[8], p[8];
#pragma unroll
        for (int t = 0; t < 8; ++t) e[t] = eb[2 * t + hf];
#pragma unroll
        for (int t = 0; t < 8; ++t) {
            int idx = (2 * t + hf < deg) ? (int)(e[t] & 0xffffu) : 0;
            p[t] = *(const unsigned int*)(hb + (size_t)idx * HID + c * 2);
        }
#pragma unroll
        for (int t = 0; t < 8; ++t) {
            float m = (2 * t + hf < deg) ? 1.0f : 0.0f;
            float v = (float)(e[t] >> 16) * qs;
            float wm = m * (1.0f - v), vm = m * v;
            float h0 = bf2f(p[t] & 0xffffu), h1 = bf2f(p[t] >> 16);
            a00 += wm * h0; a01 += wm * h1;
            a10 += vm * h0; a11 += vm * h1;
        }
    } else {
        unsigned int e[16], p[16];
#pragma unroll
        for (int t = 0; t < 16; ++t) e[t] = eb[2 * t + hf];
#pragma unroll
        for (int t = 0; t < 16; ++t) {
            int idx = (2 * t + hf < deg) ? (int)(e[t] & 0xffffu) : 0;
            p[t] = *(const unsigned int*)(hb + (size_t)idx * HID + c * 2);
        }
#pragma unroll
        for (int t = 0; t < 16; ++t) {
            float m = (2 * t + hf < deg) ? 1.0f : 0.0f;
            float v = (float)(e[t] >> 16) * qs;
            float wm = m * (1.0f - v), vm = m * v;
            float h0 = bf2f(p[t] & 0xffffu), h1 = bf2f(p[t] >> 16);
            a00 += wm * h0; a01 += wm * h1;
            a10 += vm * h0; a11 += vm * h1;
        }
        if (deg > 32) {
            for (int j = 32 + hf; j < deg; j += 2) {
                unsigned int ee = eb[j];
                int idx = (int)(ee & 0xffffu);
                unsigned int pp = *(const unsigned int*)(hb + (size_t)idx * HID + c * 2);
                float v = (float)(ee >> 16) * qs;
                float w = 1.0f - v;
                float h0 = bf2f(pp & 0xffffu), h1 = bf2f(pp >> 16);
                a00 += w * h0; a01 += w * h1;
                a10 += v * h0; a11 += v * h1;
            }
        }
    }
    a00 += __shfl_xor(a00, 32);
    a01 += __shfl_xor(a01, 32);
    a10 += __shfl_xor(a10, 32);
    a11 += __shfl_xor(a11, 32);
    if (hf == 0) {
        float dg = (float)deg;
        dg = dg > 1.0f ? dg : 1.0f;
        float inv = 1.0f / dg;
        unsigned int u0 = (unsigned int)f2bf(a00 * inv) | ((unsigned int)f2bf(a01 * inv) << 16);
        unsigned int u1 = (unsigned int)f2bf(a10 * inv) | ((unsigned int)f2bf(a11 * inv) << 16);
        *(unsigned int*)(A128 + (size_t)wave * 128 + c * 2) = u0;
        *(unsigned int*)(A128 + (size_t)wave * 128 + 64 + c * 2) = u1;
    }
}

// ---------------- layer-2 output GEMM (r10-proven): dual-source A, f32 out ----------
__global__ __launch_bounds__(256) void gemm_out(const unsigned short* __restrict__ A128,
                                                const unsigned short* __restrict__ hb,
                                                const unsigned short* __restrict__ WT2,
                                                const float* __restrict__ bias2,
                                                float* __restrict__ out) {
    constexpr int KD = K2, KP = KD + 8;      // 200
    __shared__ unsigned short As[64 * KP];   // 25.6 KB
    int tid = threadIdx.x;
    int row0 = blockIdx.x * 64;

    for (int cidx = tid; cidx < 64 * (KD / 8); cidx += 256) {  // 1536 sh8 chunks
        int r = cidx / (KD / 8), q = cidx % (KD / 8);
        int gr = row0 + r;
        sh8 v = {};
        if (gr < N_NODES) {
            if (q < 16) v = *(const sh8*)(A128 + (size_t)gr * 128 + q * 8);
            else        v = *(const sh8*)(hb + (size_t)gr * 64 + (q - 16) * 8);
        }
        *(sh8*)&As[r * KP + q * 8] = v;
    }
    __syncthreads();

    int wv = tid >> 6, lane = tid & 63;
    int lrow = lane & 15, lq = lane >> 4;
    floatx4 acc[4] = {{0.f,0.f,0.f,0.f},{0.f,0.f,0.f,0.f},{0.f,0.f,0.f,0.f},{0.f,0.f,0.f,0.f}};
#pragma unroll
    for (int kt = 0; kt < KD / 32; ++kt) {   // 6
        int kb = kt * 32 + lq * 8;
        sh8 a0 = *(const sh8*)&As[(wv * 16 + lrow) * KP + kb];
#pragma unroll
        for (int cf = 0; cf < 4; ++cf) {
            sh8 b = *(const sh8*)(WT2 + (size_t)(cf * 16 + lrow) * KD + kb);
            acc[cf] = __builtin_amdgcn_mfma_f32_16x16x32_bf16(a0, b, acc[cf], 0, 0, 0);
        }
    }
#pragma unroll
    for (int r = 0; r < 4; ++r) {
        int gr = row0 + wv * 16 + lq * 4 + r;
        if (gr >= N_NODES) continue;
#pragma unroll
        for (int cf = 0; cf < 4; ++cf) {
            int gc = cf * 16 + lrow;
            if (gc < N_CLS) {
                out[(size_t)gr * N_CLS + gc] = acc[cf][r] + bias2[gc];
            }
        }
    }
}

extern "C" void kernel_launch(void* const* d_in, const int* in_sizes, int n_in,
                              void* d_out, int out_size, void* d_ws, size_t ws_size,
                              hipStream_t stream) {
    const float* x     = (const float*)d_in[0];
    const int*   eidx  = (const int*)d_in[1];
    const float* eattr = (const float*)d_in[2];
    const float* W1    = (const float*)d_in[3];
    const float* root1 = (const float*)d_in[4];
    const float* bias1 = (const float*)d_in[5];
    const float* W2    = (const float*)d_in[6];
    const float* root2 = (const float*)d_in[7];
    const float* bias2 = (const float*)d_in[8];
    float* out = (float*)d_out;

    const int* src = eidx;
    const int* dst = eidx + N_EDGES;

    // workspace layout (bytes)
    char* base = (char*)d_ws;
    unsigned short* Ysp   = (unsigned short*)base;               // 50000*128*2 = 12,800,000
    float*          Yroot = (float*)(base + 12800000);           // 50000*64*4 = 12,800,000
    unsigned short* hb    = (unsigned short*)(base + 25600000);  // 50000*64*2 = 6,400,000
    unsigned short* WT1   = (unsigned short*)(base + 32000000);  // 192*128*2 = 49,152
    unsigned short* WT2   = (unsigned short*)(base + 32049152);  // 64*192*2 = 24,576
    unsigned int*   edata = (unsigned int*)(base + 32073728);    // 50000*64*4 = 12,800,000
    int*            cnt   = (int*)(base + 44873728);             // 50,000*4 = 200,000
    unsigned short* A128  = (unsigned short*)(base + 45073728);  // 50000*128*2 = 12,800,000

    const int GB = (N_NODES + 63) / 64;  // 782 gemm blocks

    // ---- stage 1: weights + cnt zeroing ----
    hipLaunchKernelGGL(concat_w, dim3((NW + N_NODES + 255) / 256), dim3(256), 0, stream,
                       W1, root1, W2, root2, WT1, WT2, cnt);

    // ---- stage 2: layer-1 GEMM fused with full bucketed permute (r8-proven) ----
    hipLaunchKernelGGL(gemm1_permute, dim3(GB + 8 * PERM_SLICES), dim3(256), 0, stream,
                       x, WT1, Ysp, Yroot, src, dst, eattr, cnt, edata, GB);

    // ---- stage 3: layer-1 gather (hb only — duplicate A192 write trimmed) ----
    hipLaunchKernelGGL(gather1, dim3((N_NODES * 64 + 255) / 256), dim3(256), 0, stream,
                       Ysp, Yroot, cnt, edata, bias1, hb);

    // ---- stage 4: layer-2 gather in h-space ----
    hipLaunchKernelGGL(gather2h, dim3((N_NODES * 64 + 255) / 256), dim3(256), 0, stream,
                       hb, cnt, edata, A128);

    // ---- stage 5: layer-2 output GEMM (W2 + root2 + bias2 fused, f32 out) ----
    hipLaunchKernelGGL(gemm_out, dim3(GB), dim3(256), 0, stream,
                       A128, hb, WT2, bias2, out);
}